// Round 3
// baseline (452.961 us; speedup 1.0000x reference)
//
#include <hip/hip_runtime.h>

#define NN 512
#define DD 256

typedef float f32x4 __attribute__((ext_vector_type(4)));
typedef short s16x8 __attribute__((ext_vector_type(8)));

__device__ __forceinline__ unsigned short f2bf(float f) {
    unsigned u = __float_as_uint(f);
    u += 0x7fffu + ((u >> 16) & 1u);   // round-to-nearest-even
    return (unsigned short)(u >> 16);
}

// ---------------------------------------------------------------------------
// K1: hb = h@W1.T + t_bias (broadcast), hW2 = h@W2.T, hW4 = h@W4.T,
//     w3b = bf16(W3). Blocks 0..63: 8 h-rows each (tb computed redundantly
//     per block to avoid inter-block dependency). Block 64: w3b conversion.
// ---------------------------------------------------------------------------
__global__ __launch_bounds__(256) void k1_pre(
    const float* __restrict__ h,  const float* __restrict__ W1,
    const float* __restrict__ W2, const float* __restrict__ W4,
    const float* __restrict__ t_emb, const float* __restrict__ W_t,
    const float* __restrict__ W3,
    float* __restrict__ hb, float* __restrict__ hW2, float* __restrict__ hW4,
    unsigned short* __restrict__ w3b)
{
    __shared__ float xs[8][DD];
    __shared__ float st[DD];
    const int b = blockIdx.x;
    const int t = threadIdx.x;
    if (b < 64) {
        #pragma unroll
        for (int r = 0; r < 8; ++r) xs[r][t] = h[(size_t)(b * 8 + r) * DD + t];
        st[t] = t_emb[t];
        __syncthreads();
        float a1[8], a2[8], a4[8];
        #pragma unroll
        for (int r = 0; r < 8; ++r) { a1[r] = 0.f; a2[r] = 0.f; a4[r] = 0.f; }
        float tb = 0.f;
        for (int d = 0; d < DD; ++d) {
            const float w1 = W1[(size_t)t * DD + d];
            const float w2 = W2[(size_t)t * DD + d];
            const float w4 = W4[(size_t)t * DD + d];
            tb = fmaf(st[d], W_t[(size_t)t * DD + d], tb);
            #pragma unroll
            for (int r = 0; r < 8; ++r) {
                const float x = xs[r][d];
                a1[r] = fmaf(x, w1, a1[r]);
                a2[r] = fmaf(x, w2, a2[r]);
                a4[r] = fmaf(x, w4, a4[r]);
            }
        }
        #pragma unroll
        for (int r = 0; r < 8; ++r) {
            const size_t o = (size_t)(b * 8 + r) * DD + t;
            hb[o] = a1[r] + tb; hW2[o] = a2[r]; hW4[o] = a4[r];
        }
    } else {
        // vectorized W3 -> bf16
        for (int c = t; c < DD * DD / 4; c += 256) {
            const f32x4 v = *reinterpret_cast<const f32x4*>(W3 + (size_t)c * 4);
            const unsigned lo = ((unsigned)f2bf(v[1]) << 16) | f2bf(v[0]);
            const unsigned hi = ((unsigned)f2bf(v[3]) << 16) | f2bf(v[2]);
            *reinterpret_cast<uint2*>(w3b + (size_t)c * 4) = make_uint2(lo, hi);
        }
    }
}

// ---------------------------------------------------------------------------
// K2: pre = e@W3.T + hb[i] + hW2[j] ; e_new = relu(LN(pre));
//     logits[i*512+j] = dot(e_new, gate_w) + gate_b.
// Barrier-free: 4 independent waves per block; wave w owns 16 rows
// (row_base + w*16 .. +15) x all 256 cols. A (e rows) loaded straight from
// global into 32 VGPRs (bf16), B (w3b) streamed from L2, 16 MFMA chains.
// LN + gate fully wave-local (in-lane over 16 n-frags + 4-step shfl).
// ---------------------------------------------------------------------------
__global__ __launch_bounds__(256, 3) void k2_big(
    const float* __restrict__ e,
    const unsigned short* __restrict__ w3b,
    const float* __restrict__ hb, const float* __restrict__ hW2,
    const float* __restrict__ gate_w, const float* __restrict__ gate_b,
    const float* __restrict__ ln_e_w, const float* __restrict__ ln_e_b,
    float* __restrict__ out_e, float* __restrict__ logits)
{
    const int row_base = blockIdx.x * 64;     // flat row = i*512 + j
    const int i = row_base >> 9;
    const int tid = threadIdx.x;
    const int w = tid >> 6;
    const int l = tid & 63;
    const int l15 = l & 15;
    const int lg = l >> 4;                    // 0..3
    const int g0 = row_base + w * 16;         // wave's first global flat row

    // ---- load this lane's A row (row g0+l15), all 8 K-steps, cvt to bf16 ----
    const float* arow = e + (size_t)(g0 + l15) * DD + lg * 8;
    s16x8 abf[8];
    #pragma unroll
    for (int kk = 0; kk < 8; ++kk) {
        const f32x4 v0 = *reinterpret_cast<const f32x4*>(arow + kk * 32);
        const f32x4 v1 = *reinterpret_cast<const f32x4*>(arow + kk * 32 + 4);
        s16x8 a;
        a[0] = (short)f2bf(v0[0]); a[1] = (short)f2bf(v0[1]);
        a[2] = (short)f2bf(v0[2]); a[3] = (short)f2bf(v0[3]);
        a[4] = (short)f2bf(v1[0]); a[5] = (short)f2bf(v1[1]);
        a[6] = (short)f2bf(v1[2]); a[7] = (short)f2bf(v1[3]);
        abf[kk] = a;
    }

    f32x4 acc[16];
    #pragma unroll
    for (int n = 0; n < 16; ++n) acc[n] = (f32x4){0.f, 0.f, 0.f, 0.f};

    // B base for this lane: col = n*16 + l15, k-slice = kk*32 + lg*8
    const unsigned short* bp = w3b + (size_t)l15 * DD + lg * 8;
    #pragma unroll
    for (int kk = 0; kk < 8; ++kk) {
        #pragma unroll
        for (int n = 0; n < 16; ++n) {
            const s16x8 bfr = *reinterpret_cast<const s16x8*>(bp + (size_t)n * 16 * DD + kk * 32);
            acc[n] = __builtin_amdgcn_mfma_f32_16x16x32_bf16(abf[kk], bfr, acc[n], 0, 0, 0);
        }
    }

    // ---- epilogue: biases + LN stats (wave-local) ----
    float hbn[16];
    #pragma unroll
    for (int n = 0; n < 16; ++n) hbn[n] = hb[(size_t)i * DD + n * 16 + l15];

    float mu4[4], rs4[4];
    #pragma unroll
    for (int q = 0; q < 4; ++q) {
        const int jrow = (g0 + lg * 4 + q) & 511;
        const float* h2p = hW2 + (size_t)jrow * DD + l15;
        float s1 = 0.f, s2 = 0.f;
        #pragma unroll
        for (int n = 0; n < 16; ++n) {
            float v = acc[n][q] + hbn[n] + h2p[n * 16];
            acc[n][q] = v;
            s1 += v;
            s2 = fmaf(v, v, s2);
        }
        #pragma unroll
        for (int s = 1; s < 16; s <<= 1) {
            s1 += __shfl_xor(s1, s, 64);
            s2 += __shfl_xor(s2, s, 64);
        }
        const float mu = s1 * (1.f / 256.f);
        mu4[q] = mu;
        rs4[q] = rsqrtf(s2 * (1.f / 256.f) - mu * mu + 1e-5f);
    }

    // ---- normalize, relu, store e_new, gate logits ----
    float gl[4] = {0.f, 0.f, 0.f, 0.f};
    #pragma unroll
    for (int n = 0; n < 16; ++n) {
        const int col = n * 16 + l15;
        const float lw = ln_e_w[col];
        const float lb = ln_e_b[col];
        const float gw = gate_w[col];
        #pragma unroll
        for (int q = 0; q < 4; ++q) {
            float v = (acc[n][q] - mu4[q]) * rs4[q] * lw + lb;
            v = fmaxf(v, 0.f);
            out_e[(size_t)(g0 + lg * 4 + q) * DD + col] = v;
            gl[q] = fmaf(v, gw, gl[q]);
        }
    }
    const float gb = gate_b[0];
    #pragma unroll
    for (int q = 0; q < 4; ++q) {
        #pragma unroll
        for (int s = 1; s < 16; s <<= 1) gl[q] += __shfl_xor(gl[q], s, 64);
        if (l15 == 0) logits[(size_t)(g0 + lg * 4 + q)] = gl[q] + gb;
    }
}

// ---------------------------------------------------------------------------
// K3: per i: eta = softmax_j(logits[i,:]); weighted[i,k] = sum_j eta[j]*e_new[i,j,k]
// ---------------------------------------------------------------------------
__global__ __launch_bounds__(256) void k3_soft(
    const float* __restrict__ logits, const float* __restrict__ out_e,
    float* __restrict__ weighted)
{
    const int i = blockIdx.x;
    const int t = threadIdx.x;
    const int w = t >> 6;
    const int l = t & 63;
    __shared__ float seta[NN];
    __shared__ float red[256];
    __shared__ float red2[4][DD];

    const float l0 = logits[(size_t)i * NN + t];
    const float l1 = logits[(size_t)i * NN + 256 + t];

    red[t] = fmaxf(l0, l1);
    __syncthreads();
    for (int s = 128; s > 0; s >>= 1) {
        if (t < s) red[t] = fmaxf(red[t], red[t + s]);
        __syncthreads();
    }
    const float mx = red[0];
    __syncthreads();

    const float e0 = expf(l0 - mx);
    const float e1 = expf(l1 - mx);
    red[t] = e0 + e1;
    __syncthreads();
    for (int s = 128; s > 0; s >>= 1) {
        if (t < s) red[t] += red[t + s];
        __syncthreads();
    }
    const float inv = 1.f / red[0];
    seta[t] = e0 * inv;
    seta[256 + t] = e1 * inv;
    __syncthreads();

    const float* base = out_e + (size_t)i * NN * DD;
    f32x4 a0 = (f32x4){0.f, 0.f, 0.f, 0.f};
    f32x4 a1v = (f32x4){0.f, 0.f, 0.f, 0.f};
    for (int j0 = 0; j0 < NN; j0 += 8) {
        const int ja = j0 + w;
        const int jb = j0 + 4 + w;
        const float ea = seta[ja];
        const float eb = seta[jb];
        const f32x4 va = *reinterpret_cast<const f32x4*>(base + (size_t)ja * DD + l * 4);
        const f32x4 vb = *reinterpret_cast<const f32x4*>(base + (size_t)jb * DD + l * 4);
        #pragma unroll
        for (int q = 0; q < 4; ++q) {
            a0[q] = fmaf(ea, va[q], a0[q]);
            a1v[q] = fmaf(eb, vb[q], a1v[q]);
        }
    }
    #pragma unroll
    for (int q = 0; q < 4; ++q) a0[q] += a1v[q];
    *reinterpret_cast<f32x4*>(&red2[w][l * 4]) = a0;
    __syncthreads();
    weighted[(size_t)i * DD + t] = red2[0][t] + red2[1][t] + red2[2][t] + red2[3][t];
}

// ---------------------------------------------------------------------------
// K4: h_new = h + relu(LN(hW4 + weighted@W5.T))
// ---------------------------------------------------------------------------
__global__ __launch_bounds__(256) void k4_final(
    const float* __restrict__ weighted, const float* __restrict__ W5,
    const float* __restrict__ hW4, const float* __restrict__ h,
    const float* __restrict__ ln_h_w, const float* __restrict__ ln_h_b,
    float* __restrict__ out_h)
{
    const int i = blockIdx.x;
    const int k = threadIdx.x;
    __shared__ float xs[DD];
    __shared__ float red[256];

    xs[k] = weighted[(size_t)i * DD + k];
    __syncthreads();
    float a = 0.f;
    for (int d = 0; d < DD; ++d) a = fmaf(xs[d], W5[(size_t)k * DD + d], a);
    const float p = hW4[(size_t)i * DD + k] + a;

    red[k] = p;
    __syncthreads();
    for (int s = 128; s > 0; s >>= 1) {
        if (k < s) red[k] += red[k + s];
        __syncthreads();
    }
    const float mu = red[0] * (1.f / 256.f);
    __syncthreads();
    const float d0 = p - mu;
    red[k] = d0 * d0;
    __syncthreads();
    for (int s = 128; s > 0; s >>= 1) {
        if (k < s) red[k] += red[k + s];
        __syncthreads();
    }
    const float rs = rsqrtf(red[0] * (1.f / 256.f) + 1e-5f);
    float v = d0 * rs * ln_h_w[k] + ln_h_b[k];
    v = fmaxf(v, 0.f);
    out_h[(size_t)i * DD + k] = h[(size_t)i * DD + k] + v;
}

// ---------------------------------------------------------------------------
extern "C" void kernel_launch(void* const* d_in, const int* in_sizes, int n_in,
                              void* d_out, int out_size, void* d_ws, size_t ws_size,
                              hipStream_t stream)
{
    const float* h      = (const float*)d_in[0];
    const float* e      = (const float*)d_in[1];
    const float* t_emb  = (const float*)d_in[2];
    const float* W1     = (const float*)d_in[3];
    const float* W2     = (const float*)d_in[4];
    const float* W3     = (const float*)d_in[5];
    const float* W_t    = (const float*)d_in[6];
    const float* W4     = (const float*)d_in[7];
    const float* W5     = (const float*)d_in[8];
    const float* gate_w = (const float*)d_in[9];
    const float* gate_b = (const float*)d_in[10];
    const float* ln_e_w = (const float*)d_in[11];
    const float* ln_e_b = (const float*)d_in[12];
    const float* ln_h_w = (const float*)d_in[13];
    const float* ln_h_b = (const float*)d_in[14];

    float* out_h = (float*)d_out;
    float* out_e = out_h + NN * DD;

    // workspace layout
    float* wsf      = (float*)d_ws;
    float* hb       = wsf;                    // 131072 (hW1 + t_bias)
    float* hW2      = hb + NN * DD;           // 131072
    float* hW4      = hW2 + NN * DD;          // 131072
    float* logits   = hW4 + NN * DD;          // 262144
    float* weighted = logits + NN * NN;       // 131072
    unsigned short* w3b = (unsigned short*)(weighted + NN * DD);  // 65536 ushort

    k1_pre<<<65, 256, 0, stream>>>(h, W1, W2, W4, t_emb, W_t, W3,
                                   hb, hW2, hW4, w3b);
    k2_big<<<4096, 256, 0, stream>>>(e, w3b, hb, hW2, gate_w, gate_b,
                                     ln_e_w, ln_e_b, out_e, logits);
    k3_soft<<<512, 256, 0, stream>>>(logits, out_e, weighted);
    k4_final<<<512, 256, 0, stream>>>(weighted, W5, hW4, h, ln_h_w, ln_h_b, out_h);
}

// Round 4
// 325.444 us; speedup vs baseline: 1.3918x; 1.3918x over previous
//
#include <hip/hip_runtime.h>

#define NN 512
#define DD 256

typedef float f32x4 __attribute__((ext_vector_type(4)));
typedef short s16x8 __attribute__((ext_vector_type(8)));

__device__ __forceinline__ unsigned short f2bf(float f) {
    unsigned u = __float_as_uint(f);
    u += 0x7fffu + ((u >> 16) & 1u);   // round-to-nearest-even
    return (unsigned short)(u >> 16);
}

// ---------------------------------------------------------------------------
// K1: hb = h@W1.T + t_bias, hW2 = h@W2.T, hW4 = h@W4.T, w3b = bf16(W3).
// ---------------------------------------------------------------------------
__global__ __launch_bounds__(256) void k1_pre(
    const float* __restrict__ h,  const float* __restrict__ W1,
    const float* __restrict__ W2, const float* __restrict__ W4,
    const float* __restrict__ t_emb, const float* __restrict__ W_t,
    const float* __restrict__ W3,
    float* __restrict__ hb, float* __restrict__ hW2, float* __restrict__ hW4,
    unsigned short* __restrict__ w3b)
{
    __shared__ float xs[8][DD];
    __shared__ float st[DD];
    const int b = blockIdx.x;
    const int t = threadIdx.x;
    if (b < 64) {
        #pragma unroll
        for (int r = 0; r < 8; ++r) xs[r][t] = h[(size_t)(b * 8 + r) * DD + t];
        st[t] = t_emb[t];
        __syncthreads();
        float a1[8], a2[8], a4[8];
        #pragma unroll
        for (int r = 0; r < 8; ++r) { a1[r] = 0.f; a2[r] = 0.f; a4[r] = 0.f; }
        float tb = 0.f;
        for (int d = 0; d < DD; ++d) {
            const float w1 = W1[(size_t)t * DD + d];
            const float w2 = W2[(size_t)t * DD + d];
            const float w4 = W4[(size_t)t * DD + d];
            tb = fmaf(st[d], W_t[(size_t)t * DD + d], tb);
            #pragma unroll
            for (int r = 0; r < 8; ++r) {
                const float x = xs[r][d];
                a1[r] = fmaf(x, w1, a1[r]);
                a2[r] = fmaf(x, w2, a2[r]);
                a4[r] = fmaf(x, w4, a4[r]);
            }
        }
        #pragma unroll
        for (int r = 0; r < 8; ++r) {
            const size_t o = (size_t)(b * 8 + r) * DD + t;
            hb[o] = a1[r] + tb; hW2[o] = a2[r]; hW4[o] = a4[r];
        }
    } else {
        for (int c = t; c < DD * DD / 4; c += 256) {
            const f32x4 v = *reinterpret_cast<const f32x4*>(W3 + (size_t)c * 4);
            const unsigned lo = ((unsigned)f2bf(v[1]) << 16) | f2bf(v[0]);
            const unsigned hi = ((unsigned)f2bf(v[3]) << 16) | f2bf(v[2]);
            *reinterpret_cast<uint2*>(w3b + (size_t)c * 4) = make_uint2(lo, hi);
        }
    }
}

// ---------------------------------------------------------------------------
// K2: pre = e@W3.T + hb[i] + hW2[j] ; e_new = relu(LN(pre));
//     logits = e_new@gate_w + gate_b.
// Block = 32 rows (i fixed), 4 waves; wave w owns cols [w*64, w*64+64).
// acc[2][4] (32 AGPR) keeps total regs ~112 -> ~4 waves/SIMD.
// A staged once in LDS (bf16, XOR swizzle); B double-buffered in regs
// (kk=0 loads hoisted above the barrier to overlap A-staging latency).
// ---------------------------------------------------------------------------
__global__ __launch_bounds__(256) void k2_big(
    const float* __restrict__ e,
    const unsigned short* __restrict__ w3b,
    const float* __restrict__ hb, const float* __restrict__ hW2,
    const float* __restrict__ gate_w, const float* __restrict__ gate_b,
    const float* __restrict__ ln_e_w, const float* __restrict__ ln_e_b,
    float* __restrict__ out_e, float* __restrict__ logits)
{
    const int row_base = blockIdx.x * 32;     // flat row = i*512 + j
    const int i = row_base >> 9;
    const int tid = threadIdx.x;
    const int w = tid >> 6;
    const int l = tid & 63;
    const int l15 = l & 15;
    const int lg = l >> 4;                    // 0..3

    __shared__ __align__(16) unsigned char sA[32 * 256 * 2];   // 16 KiB bf16, swizzled
    __shared__ float s_part[32][4][2];
    __shared__ float s_mu[32];
    __shared__ float s_rs[32];
    __shared__ float s_glog[32][4];

    // ---- issue A-tile global loads (8 x f32x4 per thread) ----
    const float* src = e + (size_t)row_base * DD;
    f32x4 av[8];
    #pragma unroll
    for (int s = 0; s < 8; ++s)
        av[s] = *reinterpret_cast<const f32x4*>(src + (size_t)(s * 256 + tid) * 4);

    // ---- issue kk=0 B-fragment loads (overlap with staging below) ----
    const unsigned short* bp = w3b + (size_t)(w * 64 + l15) * DD + lg * 8;
    s16x8 bcur[4];
    #pragma unroll
    for (int n = 0; n < 4; ++n)
        bcur[n] = *reinterpret_cast<const s16x8*>(bp + (size_t)n * 16 * DD);

    // ---- convert + store A to swizzled LDS ----
    #pragma unroll
    for (int s = 0; s < 8; ++s) {
        const int flat = s * 256 + tid;          // f32x4 chunk id
        const int r = flat >> 6;                 // row 0..31
        const int c4 = (flat & 63) * 4;          // col (multiple of 4)
        const f32x4 v = av[s];
        const unsigned lo = ((unsigned)f2bf(v[1]) << 16) | f2bf(v[0]);
        const unsigned hi = ((unsigned)f2bf(v[3]) << 16) | f2bf(v[2]);
        const unsigned byte = ((unsigned)(r * 512 + c4 * 2)) ^ ((unsigned)(r & 7) << 4);
        *reinterpret_cast<uint2*>(sA + byte) = make_uint2(lo, hi);
    }
    __syncthreads();

    f32x4 acc[2][4];
    #pragma unroll
    for (int m = 0; m < 2; ++m)
        #pragma unroll
        for (int n = 0; n < 4; ++n)
            acc[m][n] = (f32x4){0.f, 0.f, 0.f, 0.f};

    const unsigned aswz = ((unsigned)(l15 & 7) << 4);
    #pragma unroll
    for (int kk = 0; kk < 8; ++kk) {
        s16x8 bnxt[4];
        if (kk < 7) {
            #pragma unroll
            for (int n = 0; n < 4; ++n)
                bnxt[n] = *reinterpret_cast<const s16x8*>(bp + (size_t)n * 16 * DD + (kk + 1) * 32);
        }
        s16x8 afr[2];
        #pragma unroll
        for (int m = 0; m < 2; ++m) {
            const unsigned byte = ((unsigned)((m * 16 + l15) * 512 + kk * 64 + lg * 16)) ^ aswz;
            afr[m] = *reinterpret_cast<const s16x8*>(sA + byte);
        }
        #pragma unroll
        for (int n = 0; n < 4; ++n)
            #pragma unroll
            for (int m = 0; m < 2; ++m)
                acc[m][n] = __builtin_amdgcn_mfma_f32_16x16x32_bf16(afr[m], bcur[n], acc[m][n], 0, 0, 0);
        if (kk < 7) {
            #pragma unroll
            for (int n = 0; n < 4; ++n) bcur[n] = bnxt[n];
        }
    }

    // ---- epilogue: biases + LN stats (cross-wave via LDS) ----
    float hbn[4], lnwc[4], lnbc[4], gwc[4];
    #pragma unroll
    for (int n = 0; n < 4; ++n) {
        const int col = w * 64 + n * 16 + l15;
        hbn[n]  = hb[(size_t)i * DD + col];
        lnwc[n] = ln_e_w[col];
        lnbc[n] = ln_e_b[col];
        gwc[n]  = gate_w[col];
    }

    #pragma unroll
    for (int m = 0; m < 2; ++m) {
        #pragma unroll
        for (int q = 0; q < 4; ++q) {
            const int r = m * 16 + lg * 4 + q;           // row within block (0..31)
            const int j = (row_base + r) & 511;
            const float* h2p = hW2 + (size_t)j * DD + w * 64 + l15;
            float s1 = 0.f, s2 = 0.f;
            #pragma unroll
            for (int n = 0; n < 4; ++n) {
                float v = acc[m][n][q] + hbn[n] + h2p[n * 16];
                acc[m][n][q] = v;
                s1 += v;
                s2 = fmaf(v, v, s2);
            }
            #pragma unroll
            for (int s = 1; s < 16; s <<= 1) {
                s1 += __shfl_xor(s1, s, 64);
                s2 += __shfl_xor(s2, s, 64);
            }
            if (l15 == 0) { s_part[r][w][0] = s1; s_part[r][w][1] = s2; }
        }
    }
    __syncthreads();
    if (tid < 32) {
        float S1 = 0.f, S2 = 0.f;
        #pragma unroll
        for (int ww = 0; ww < 4; ++ww) { S1 += s_part[tid][ww][0]; S2 += s_part[tid][ww][1]; }
        const float mu = S1 * (1.f / 256.f);
        const float var = S2 * (1.f / 256.f) - mu * mu;
        s_mu[tid] = mu;
        s_rs[tid] = rsqrtf(var + 1e-5f);
    }
    __syncthreads();

    #pragma unroll
    for (int m = 0; m < 2; ++m) {
        #pragma unroll
        for (int q = 0; q < 4; ++q) {
            const int r = m * 16 + lg * 4 + q;
            const float mu = s_mu[r];
            const float rs = s_rs[r];
            const size_t rowg = (size_t)(row_base + r);
            float gl = 0.f;
            #pragma unroll
            for (int n = 0; n < 4; ++n) {
                const int col = w * 64 + n * 16 + l15;
                float v = (acc[m][n][q] - mu) * rs * lnwc[n] + lnbc[n];
                v = fmaxf(v, 0.f);
                out_e[rowg * DD + col] = v;
                gl = fmaf(v, gwc[n], gl);
            }
            #pragma unroll
            for (int s = 1; s < 16; s <<= 1) gl += __shfl_xor(gl, s, 64);
            if (l15 == 0) s_glog[r][w] = gl;
        }
    }
    __syncthreads();
    if (tid < 32) {
        float g = gate_b[0];
        #pragma unroll
        for (int ww = 0; ww < 4; ++ww) g += s_glog[tid][ww];
        logits[(size_t)row_base + tid] = g;
    }
}

// ---------------------------------------------------------------------------
// K3: per i: eta = softmax_j(logits[i,:]); weighted[i,k] = sum_j eta[j]*e_new[i,j,k]
// ---------------------------------------------------------------------------
__global__ __launch_bounds__(256) void k3_soft(
    const float* __restrict__ logits, const float* __restrict__ out_e,
    float* __restrict__ weighted)
{
    const int i = blockIdx.x;
    const int t = threadIdx.x;
    const int w = t >> 6;
    const int l = t & 63;
    __shared__ float seta[NN];
    __shared__ float red[256];
    __shared__ float red2[4][DD];

    const float l0 = logits[(size_t)i * NN + t];
    const float l1 = logits[(size_t)i * NN + 256 + t];

    red[t] = fmaxf(l0, l1);
    __syncthreads();
    for (int s = 128; s > 0; s >>= 1) {
        if (t < s) red[t] = fmaxf(red[t], red[t + s]);
        __syncthreads();
    }
    const float mx = red[0];
    __syncthreads();

    const float e0 = expf(l0 - mx);
    const float e1 = expf(l1 - mx);
    red[t] = e0 + e1;
    __syncthreads();
    for (int s = 128; s > 0; s >>= 1) {
        if (t < s) red[t] += red[t + s];
        __syncthreads();
    }
    const float inv = 1.f / red[0];
    seta[t] = e0 * inv;
    seta[256 + t] = e1 * inv;
    __syncthreads();

    const float* base = out_e + (size_t)i * NN * DD;
    f32x4 a0 = (f32x4){0.f, 0.f, 0.f, 0.f};
    f32x4 a1v = (f32x4){0.f, 0.f, 0.f, 0.f};
    for (int j0 = 0; j0 < NN; j0 += 8) {
        const int ja = j0 + w;
        const int jb = j0 + 4 + w;
        const float ea = seta[ja];
        const float eb = seta[jb];
        const f32x4 va = *reinterpret_cast<const f32x4*>(base + (size_t)ja * DD + l * 4);
        const f32x4 vb = *reinterpret_cast<const f32x4*>(base + (size_t)jb * DD + l * 4);
        #pragma unroll
        for (int q = 0; q < 4; ++q) {
            a0[q] = fmaf(ea, va[q], a0[q]);
            a1v[q] = fmaf(eb, vb[q], a1v[q]);
        }
    }
    #pragma unroll
    for (int q = 0; q < 4; ++q) a0[q] += a1v[q];
    *reinterpret_cast<f32x4*>(&red2[w][l * 4]) = a0;
    __syncthreads();
    weighted[(size_t)i * DD + t] = red2[0][t] + red2[1][t] + red2[2][t] + red2[3][t];
}

// ---------------------------------------------------------------------------
// K4: h_new = h + relu(LN(hW4 + weighted@W5.T))
// ---------------------------------------------------------------------------
__global__ __launch_bounds__(256) void k4_final(
    const float* __restrict__ weighted, const float* __restrict__ W5,
    const float* __restrict__ hW4, const float* __restrict__ h,
    const float* __restrict__ ln_h_w, const float* __restrict__ ln_h_b,
    float* __restrict__ out_h)
{
    const int i = blockIdx.x;
    const int k = threadIdx.x;
    __shared__ float xs[DD];
    __shared__ float red[256];

    xs[k] = weighted[(size_t)i * DD + k];
    __syncthreads();
    float a = 0.f;
    for (int d = 0; d < DD; ++d) a = fmaf(xs[d], W5[(size_t)k * DD + d], a);
    const float p = hW4[(size_t)i * DD + k] + a;

    red[k] = p;
    __syncthreads();
    for (int s = 128; s > 0; s >>= 1) {
        if (k < s) red[k] += red[k + s];
        __syncthreads();
    }
    const float mu = red[0] * (1.f / 256.f);
    __syncthreads();
    const float d0 = p - mu;
    red[k] = d0 * d0;
    __syncthreads();
    for (int s = 128; s > 0; s >>= 1) {
        if (k < s) red[k] += red[k + s];
        __syncthreads();
    }
    const float rs = rsqrtf(red[0] * (1.f / 256.f) + 1e-5f);
    float v = d0 * rs * ln_h_w[k] + ln_h_b[k];
    v = fmaxf(v, 0.f);
    out_h[(size_t)i * DD + k] = h[(size_t)i * DD + k] + v;
}

// ---------------------------------------------------------------------------
extern "C" void kernel_launch(void* const* d_in, const int* in_sizes, int n_in,
                              void* d_out, int out_size, void* d_ws, size_t ws_size,
                              hipStream_t stream)
{
    const float* h      = (const float*)d_in[0];
    const float* e      = (const float*)d_in[1];
    const float* t_emb  = (const float*)d_in[2];
    const float* W1     = (const float*)d_in[3];
    const float* W2     = (const float*)d_in[4];
    const float* W3     = (const float*)d_in[5];
    const float* W_t    = (const float*)d_in[6];
    const float* W4     = (const float*)d_in[7];
    const float* W5     = (const float*)d_in[8];
    const float* gate_w = (const float*)d_in[9];
    const float* gate_b = (const float*)d_in[10];
    const float* ln_e_w = (const float*)d_in[11];
    const float* ln_e_b = (const float*)d_in[12];
    const float* ln_h_w = (const float*)d_in[13];
    const float* ln_h_b = (const float*)d_in[14];

    float* out_h = (float*)d_out;
    float* out_e = out_h + NN * DD;

    // workspace layout
    float* wsf      = (float*)d_ws;
    float* hb       = wsf;                    // 131072 (hW1 + t_bias)
    float* hW2      = hb + NN * DD;           // 131072
    float* hW4      = hW2 + NN * DD;          // 131072
    float* logits   = hW4 + NN * DD;          // 262144
    float* weighted = logits + NN * NN;       // 131072
    unsigned short* w3b = (unsigned short*)(weighted + NN * DD);  // 65536 ushort

    k1_pre<<<65, 256, 0, stream>>>(h, W1, W2, W4, t_emb, W_t, W3,
                                   hb, hW2, hW4, w3b);
    k2_big<<<8192, 256, 0, stream>>>(e, w3b, hb, hW2, gate_w, gate_b,
                                     ln_e_w, ln_e_b, out_e, logits);
    k3_soft<<<512, 256, 0, stream>>>(logits, out_e, weighted);
    k4_final<<<512, 256, 0, stream>>>(weighted, W5, hW4, h, ln_h_w, ln_h_b, out_h);
}